// Round 17
// baseline (416.443 us; speedup 1.0000x reference)
//
#include <hip/hip_runtime.h>
#include <hip/hip_bf16.h>
#include <stdint.h>

#define AS1 __attribute__((address_space(1)))
#define AS3 __attribute__((address_space(3)))

typedef __attribute__((ext_vector_type(8))) short short8v;
typedef __attribute__((ext_vector_type(4))) unsigned short ushort4v;
typedef __attribute__((ext_vector_type(4))) float float4v;

#define NT 64
#define CCH 256
#define HH 56
#define WW 56
#define HWSZ 3136
#define HP 58
#define WP 58
#define TAILP 196608    // first tail pixel (tiles 1536..1567)

// workspace layout (bytes)
#define OFF_XT   0ull
#define SZ_XT    110231552ull          // 64*58*58*256*2  (bf16 NHWC padded)
#define OFF_WPK  (OFF_XT + SZ_XT)
#define SZ_WPK   1179648ull            // 9*256*256*2
#define OFF_CS   (OFF_WPK + SZ_WPK)
#define SZ_CS    65536ull              // 64*256 f32 channel sums
#define OFF_XG2  (OFF_CS + SZ_CS)
#define SZ_XG2   8192ull               // 8*256 f32
#define OFF_WGT  (OFF_XG2 + SZ_XG2)
#define SZ_WGT   24576ull              // 8*256*3 f32
#define OFF_GATE (OFF_WGT + SZ_WGT)
#define SZ_GATE  65536ull              // 64*256 f32
#define OFF_CVT  (OFF_GATE + SZ_GATE)
#define SZ_CVT   102760448ull          // 200704*256 bf16 conv output

__device__ __forceinline__ unsigned short f2bf(float f) {
    unsigned int u = __float_as_uint(f);
    unsigned int r = (u + 0x7fffu + ((u >> 16) & 1u)) >> 16;
    return (unsigned short)r;
}
__device__ __forceinline__ float bf2f(unsigned short u) {
    return __uint_as_float(((unsigned int)u) << 16);
}

__device__ __forceinline__ void gload16(const unsigned short* g, unsigned short* l) {
    __builtin_amdgcn_global_load_lds((const AS1 void*)g, (AS3 void*)l, 16, 0, 0);
}

// ---------------- K0: NCHW f32 -> NHWC-padded bf16 (with zero borders) ----
__global__ __launch_bounds__(256) void k0_transpose(const float* __restrict__ x,
                                                    unsigned short* __restrict__ xt) {
    int b = blockIdx.x;              // (nt, h, cb) : 64*56*4
    int cb = b & 3;
    int h  = (b >> 2) % 56;
    int nt = b / (4 * 56);
    int c0 = cb * 64;
    int tid = threadIdx.x;

    __shared__ float xs[64 * 57];    // padded stride 57 to dodge bank conflicts

    const float* src = x + ((size_t)nt * CCH + c0) * HWSZ + h * WW;
    for (int li = tid; li < 896; li += 256) {       // 64 rows * 14 float4
        int row = li / 14, f4 = li % 14;
        float4v v = *(const float4v*)(src + (size_t)row * HWSZ + f4 * 4);
        float* d = &xs[row * 57 + f4 * 4];
        d[0] = v.x; d[1] = v.y; d[2] = v.z; d[3] = v.w;
    }
    __syncthreads();

    unsigned short* dst = xt + (((size_t)nt * HP + (h + 1)) * WP) * CCH + c0;
    for (int job = tid; job < 464; job += 256) {    // 58 ww * 8 cgroups
        int ww = job >> 3, cg = job & 7;
        short8v v;
        if (ww == 0 || ww == 57) {
            v = (short8v){0,0,0,0,0,0,0,0};
        } else {
            #pragma unroll
            for (int jj = 0; jj < 8; ++jj)
                v[jj] = (short)f2bf(xs[(cg * 8 + jj) * 57 + (ww - 1)]);
        }
        *(short8v*)(dst + ww * CCH + cg * 8) = v;
    }
    if (h == 0) {   // zero rows hh=0 and hh=57
        unsigned short* d0  = xt + ((size_t)nt * HP + 0)  * WP * CCH + c0;
        unsigned short* d57 = xt + ((size_t)nt * HP + 57) * WP * CCH + c0;
        short8v z = (short8v){0,0,0,0,0,0,0,0};
        for (int job = tid; job < 464; job += 256) {
            int ww = job >> 3, cg = job & 7;
            *(short8v*)(d0  + ww * CCH + cg * 8) = z;
            *(short8v*)(d57 + ww * CCH + cg * 8) = z;
        }
    }
}

// ---------------- KW: pack conv weights -> [rs][k][c] bf16 ----------------
__global__ __launch_bounds__(256) void kw_pack(const float* __restrict__ nw,
                                               unsigned short* __restrict__ wpk) {
    int idx = blockIdx.x * 256 + threadIdx.x;       // 9*256*256 = 589824
    int rs = idx >> 16;
    int k  = (idx >> 8) & 255;
    int c  = idx & 255;
    wpk[idx] = f2bf(nw[(k * 256 + c) * 9 + rs]);
}

// ---------------- KI: init tail region of out (bias) + chansum bias terms -
// Tail pixels [196608, 200704): images 62 (hw>=2176, 960px) and 63 (all).
__global__ __launch_bounds__(256) void kinit(const float* __restrict__ net_b,
                                             float* __restrict__ out,
                                             float* __restrict__ chansum) {
    int idx = blockIdx.x * 256 + threadIdx.x;    // 1,048,576
    int m  = idx >> 12;          // 0..255
    int pp = idx & 4095;         // 0..4095
    int p  = TAILP + pp;
    int nt = p / HWSZ, hw = p - nt * HWSZ;
    out[((size_t)nt * CCH + m) * HWSZ + hw] = net_b[m];
    if (pp < 512) {              // 2 images x 256 channels
        int img = 62 + (pp >> 8);
        int mm  = pp & 255;
        float npix = (img == 62) ? 960.f : 3136.f;
        chansum[img * CCH + mm] = npix * net_b[mm];
    }
}

// ---------------- conv: implicit GEMM, 256x128x32 (R11 structure) ---------
// Blocks 0..1535: one full tile each (R11 inner loop, best measured).
// Blocks 1536..1663 (dispatched LAST): 4-way split-K quarters (18 ktiles) of
// the 32 tail tiles -> round 4 shrinks to T/4 (makespan 3.25T, was 3.5T in
// R16's 2-way, 4T in R15).  Tail partials accumulate f32 atomicAdd into out
// (kinit pre-wrote bias); k5 reads tail pixels from out(f32), rest cvt(bf16).

#define STGALL(bi_, tA_, tB_) do { \
    gload16(wpk + (tA_) + aoffg0, &lds[(bi_) * 8192 + ldsa0]); \
    gload16(wpk + (tA_) + aoffg1, &lds[(bi_) * 8192 + ldsa1]); \
    gload16(xt  + (tB_) + boffg,  &lds[24576 + (bi_) * 4096 + ldsb]); \
} while (0)

#define LDAF(mi) (*(const short8v*)&lds[abase + (wm * 64 + (mi) * 16 + r16) * 32 + pA * 8])
#define LDBF(j)  (*(const short8v*)&lds[bbase + (wp * 64 + (j) * 16 + r16) * 32 + pA * 8])

#define KTA(kt) ((((kt) >> 3) << 16) + (((kt) & 7) * 32))
#define KTB(kt) (((((kt) >> 3) / 3) * WP + (((kt) >> 3) - (((kt) >> 3) / 3) * 3)) * 256 + (((kt) & 7) * 32))

#define BARSYNC do { \
    __builtin_amdgcn_s_barrier(); \
    __builtin_amdgcn_sched_barrier(0); \
} while (0)

#define KTILE_BODY \
    short8v afrag[4], bfrag[4]; \
    _Pragma("unroll") \
    for (int mi = 0; mi < 4; ++mi) afrag[mi] = LDAF(mi); \
    _Pragma("unroll") \
    for (int j = 0; j < 4; ++j) bfrag[j] = LDBF(j); \
    asm volatile("s_waitcnt lgkmcnt(0)" ::: "memory"); \
    __builtin_amdgcn_sched_barrier(0); \
    __builtin_amdgcn_s_setprio(1); \
    _Pragma("unroll") \
    for (int j = 0; j < 4; ++j) \
        _Pragma("unroll") \
        for (int mi = 0; mi < 4; ++mi) \
            acc[mi][j] = __builtin_amdgcn_mfma_f32_16x16x32_bf16(afrag[mi], bfrag[j], acc[mi][j], 0, 0, 0); \
    __builtin_amdgcn_s_setprio(0); \
    BARSYNC;

template <int OB>
__global__ __launch_bounds__(512, 4) void conv_mfma(const unsigned short* __restrict__ xt,
                                                    const unsigned short* __restrict__ wpk,
                                                    const float* __restrict__ net_b,
                                                    float* __restrict__ out,
                                                    unsigned short* __restrict__ cvt,
                                                    float* __restrict__ chansum) {
    __shared__ unsigned short lds[36864];  // 72 KB: A ring 3x8192, B ring 3x4096

    const int tid  = threadIdx.x;
    const int lane = tid & 63;
    const int wid  = tid >> 6;         // 0..7
    const int wm   = wid >> 1;         // 0..3  (m quarter, 64 rows)
    const int wp   = wid & 1;          // 0..1  (pixel half, 64 px)
    const int r16  = lane & 15;
    const int hi   = lane >> 4;        // 0..3  (k-chunk)
    const int pA   = (hi + (r16 >> 1)) & 3;   // rotation-swizzle read position

    const int bid = blockIdx.x;

    // A staging precompute: slot s -> row r = s>>2, pos p = s&3 holds global
    // chunk cg = (p - (r>>1)) & 3; 4 lanes/row cover 64 B contiguous.
    const int cgs = ((tid & 3) - (tid >> 3)) & 3;
    const int aoffg0 = (tid >> 2) * 256 + cgs * 8;   // A rows 0..127
    const int aoffg1 = aoffg0 + 32768;               // A rows 128..255
    const int ldsa0  = tid * 8;
    const int ldsa1  = ldsa0 + 4096;
    const int ldsb   = tid * 8;

    float4v acc[4][4];
    #pragma unroll
    for (int i = 0; i < 4; ++i)
        #pragma unroll
        for (int j = 0; j < 4; ++j) acc[i][j] = (float4v){0.f, 0.f, 0.f, 0.f};

    if (bid < 1536) {
        // ---------- regular: one full tile ----------
        // XCD-aware bijective swizzle: 1536 = 8 * 192
        const int pb0 = (bid & 7) * 192 + (bid >> 3);
        const int p0 = pb0 * 128;

        long boffg;
        {
            int r = tid >> 2;              // pixel row 0..127
            int p = p0 + r;
            int nt = p / HWSZ, hw = p - nt * HWSZ;
            int hh = hw / WW,  w  = hw - hh * WW;
            boffg = ((long)(nt * HP + hh) * WP + w) * 256 + cgs * 8;
        }

        STGALL(0, 0, 0);
        STGALL(1, 32, 32);

        int cur = 0;
        for (int kt = 0; kt < 72; ++kt) {
            const int abase = cur * 8192;
            const int bbase = 24576 + cur * 4096;

            if (kt < 70) {
                const int ktn = kt + 2;
                int nb2 = cur + 2; if (nb2 >= 3) nb2 -= 3;
                STGALL(nb2, KTA(ktn), KTB(ktn));
                asm volatile("s_waitcnt vmcnt(6)" ::: "memory");
            } else if (kt == 70) {
                asm volatile("s_waitcnt vmcnt(3)" ::: "memory");
            } else {
                asm volatile("s_waitcnt vmcnt(0)" ::: "memory");
            }
            BARSYNC;

            KTILE_BODY
            ++cur; if (cur >= 3) cur = 0;
        }

        // epilogue: bias + store + fused channel-sum
        const int pw = p0 + wp * 64;
        const int ntw = pw / HWSZ;
        const int hwb = pw - ntw * HWSZ;
        #pragma unroll
        for (int mi = 0; mi < 4; ++mi) {
            #pragma unroll
            for (int r = 0; r < 4; ++r) {
                const int m = wm * 64 + mi * 16 + hi * 4 + r;
                const float bias = net_b[m];
                float csum = 0.f;
                const size_t obase = ((size_t)ntw * CCH + m) * HWSZ + hwb;
                #pragma unroll
                for (int j = 0; j < 4; ++j) {
                    float v = acc[mi][j][r] + bias;
                    if (OB) cvt[obase + j * 16 + r16] = f2bf(v);
                    else    out[obase + j * 16 + r16] = v;
                    csum += v;
                }
                csum += __shfl_xor(csum, 1);
                csum += __shfl_xor(csum, 2);
                csum += __shfl_xor(csum, 4);
                csum += __shfl_xor(csum, 8);
                if (r16 == 0) atomicAdd(&chansum[ntw * CCH + m], csum);
            }
        }
    } else {
        // ---------- tail: quarter-K of one of the 32 tail tiles ----------
        const int tb = bid - 1536;           // 0..127
        const int p0 = (1536 + (tb >> 2)) * 128;
        const int k0 = (tb & 3) * 18;

        long boffg;
        {
            int r = tid >> 2;
            int p = p0 + r;
            int nt = p / HWSZ, hw = p - nt * HWSZ;
            int hh = hw / WW,  w  = hw - hh * WW;
            boffg = ((long)(nt * HP + hh) * WP + w) * 256 + cgs * 8;
        }

        STGALL(0, KTA(k0), KTB(k0));
        STGALL(1, KTA(k0 + 1), KTB(k0 + 1));

        int cur = 0;
        for (int i = 0; i < 18; ++i) {
            const int abase = cur * 8192;
            const int bbase = 24576 + cur * 4096;

            if (i < 16) {
                int nb2 = cur + 2; if (nb2 >= 3) nb2 -= 3;
                const int ktn = k0 + i + 2;
                STGALL(nb2, KTA(ktn), KTB(ktn));
                asm volatile("s_waitcnt vmcnt(6)" ::: "memory");
            } else if (i == 16) {
                asm volatile("s_waitcnt vmcnt(3)" ::: "memory");
            } else {
                asm volatile("s_waitcnt vmcnt(0)" ::: "memory");
            }
            BARSYNC;

            KTILE_BODY
            ++cur; if (cur >= 3) cur = 0;
        }

        // tail epilogue: atomic accumulate into f32 out (no bias), csum
        const int pw = p0 + wp * 64;
        const int ntw = pw / HWSZ;
        const int hwb = pw - ntw * HWSZ;
        #pragma unroll
        for (int mi = 0; mi < 4; ++mi) {
            #pragma unroll
            for (int r = 0; r < 4; ++r) {
                const int m = wm * 64 + mi * 16 + hi * 4 + r;
                float csum = 0.f;
                float* orow = out + ((size_t)ntw * CCH + m) * HWSZ + hwb;
                #pragma unroll
                for (int j = 0; j < 4; ++j) {
                    float v = acc[mi][j][r];
                    atomicAdd(&orow[j * 16 + r16], v);
                    csum += v;
                }
                csum += __shfl_xor(csum, 1);
                csum += __shfl_xor(csum, 2);
                csum += __shfl_xor(csum, 4);
                csum += __shfl_xor(csum, 8);
                if (r16 == 0) atomicAdd(&chansum[ntw * CCH + m], csum);
            }
        }
    }
}

// ---------------- K234: fused x_g -> MLP/BN/softmax -> ME gate ------------
__global__ __launch_bounds__(256) void k234(const float* __restrict__ chansum,
                                            const float* __restrict__ lam_w,
                                            const float* __restrict__ lam_b,
                                            const float* __restrict__ mw1,
                                            const float* __restrict__ bg,
                                            const float* __restrict__ bb,
                                            const float* __restrict__ bm,
                                            const float* __restrict__ bv,
                                            const float* __restrict__ mw2,
                                            const float* __restrict__ me_w,
                                            float* __restrict__ xg2,
                                            float* __restrict__ wgt,
                                            float* __restrict__ gate) {
    int n = blockIdx.x, c = threadIdx.x;
    __shared__ float xs[256];
    __shared__ float yd[8][256];

    float s = 0.f;
    #pragma unroll
    for (int t = 0; t < 8; ++t) s += chansum[(n * 8 + t) * CCH + c];
    xs[c] = s * (1.0f / (3136.f * 8.f));
    __syncthreads();

    float xg = lam_b[c];
    const float* row = lam_w + c * 256;
    for (int cc = 0; cc < 256; ++cc) xg += row[cc] * xs[cc];
    xg2[n * 256 + c] = xg;

    float p[8];
    #pragma unroll
    for (int t = 0; t < 8; ++t)
        p[t] = chansum[(n * 8 + t) * CCH + c] * (1.0f / 3136.f) + xg;

    float hd[16];
    #pragma unroll
    for (int j = 0; j < 16; ++j) {
        float v = 0.f;
        #pragma unroll
        for (int t = 0; t < 8; ++t) v += p[t] * mw1[j * 8 + t];
        v = (v - bm[j]) * (bg[j] * rsqrtf(bv[j] + 1e-5f)) + bb[j];
        hd[j] = fmaxf(v, 0.f);
    }
    float lg[3];
    #pragma unroll
    for (int k = 0; k < 3; ++k) {
        float v = 0.f;
        #pragma unroll
        for (int j = 0; j < 16; ++j) v += hd[j] * mw2[k * 16 + j];
        lg[k] = v;
    }
    float mx = fmaxf(fmaxf(lg[0], lg[1]), lg[2]);
    float e0 = expf(lg[0] - mx), e1 = expf(lg[1] - mx), e2 = expf(lg[2] - mx);
    float inv = 1.f / (e0 + e1 + e2);
    float wk[3] = {e0 * inv, e1 * inv, e2 * inv};
    int idx = n * 256 + c;
    #pragma unroll
    for (int k = 0; k < 3; ++k) wgt[idx * 3 + k] = wk[k];

    float mb[8];
    #pragma unroll
    for (int t = 0; t < 8; ++t) {
        float v = 0.f;
        #pragma unroll
        for (int k = 0; k < 3; ++k) {
            int tt = t + k - 1;
            if (tt >= 0 && tt < 8) v += wk[k] * p[tt];
        }
        mb[t] = v;
    }
    #pragma unroll
    for (int t = 0; t < 7; ++t) yd[t][c] = mb[t + 1] - mb[t];
    yd[7][c] = 0.f;
    __syncthreads();

    float w0 = me_w[0], w1v = me_w[1], w2v = me_w[2];
    #pragma unroll
    for (int t = 0; t < 8; ++t) {
        float yc = w1v * yd[t][c];
        if (c > 0)   yc += w0 * yd[t][c - 1];
        if (c < 255) yc += w2v * yd[t][c + 1];
        gate[(n * 8 + t) * CCH + c] = 1.f / (1.f + expf(-yc));
    }
}

// ---------------- K5: temporal mix + gate -> d_out ------------------------
template <int OB>
__global__ __launch_bounds__(256) void k5_final(float* __restrict__ out,
                                                const unsigned short* __restrict__ cvt,
                                                const float* __restrict__ wgt,
                                                const float* __restrict__ xg2,
                                                const float* __restrict__ gate) {
    int tid = blockIdx.x * 256 + threadIdx.x;   // 2048 * 784
    int hw4 = tid % 784;
    int nc = tid / 784;
    int n = nc >> 8, c = nc & 255;
    float w0 = wgt[nc * 3 + 0], w1 = wgt[nc * 3 + 1], w2 = wgt[nc * 3 + 2];
    float xg = xg2[nc];
    const size_t tstride = (size_t)CCH * HWSZ;
    size_t base = ((size_t)(n * 8) * CCH + c) * HWSZ + hw4 * 4;

    float4v o[8];
    #pragma unroll
    for (int t = 0; t < 8; ++t) {
        size_t addr = base + t * tstride;
        if (OB) {
            int p = (n * 8 + t) * HWSZ + hw4 * 4;   // global pixel index
            if (p >= TAILP) {                        // tail: f32 in out
                o[t] = *(const float4v*)(out + addr);
            } else {
                ushort4v v = *(const ushort4v*)(cvt + addr);
                #pragma unroll
                for (int q = 0; q < 4; ++q) o[t][q] = bf2f(v[q]);
            }
        } else {
            o[t] = *(const float4v*)(out + addr);
        }
    }

    #pragma unroll
    for (int t = 0; t < 8; ++t) {
        float g = gate[(n * 8 + t) * CCH + c];
        float4v lam;
        #pragma unroll
        for (int q = 0; q < 4; ++q) {
            float v = w1 * (o[t][q] + xg);
            if (t > 0) v += w0 * (o[t - 1][q] + xg);
            if (t < 7) v += w2 * (o[t + 1][q] + xg);
            lam[q] = g * v;
        }
        *(float4v*)(out + base + t * tstride) = lam;
    }
}

extern "C" void kernel_launch(void* const* d_in, const int* in_sizes, int n_in,
                              void* d_out, int out_size, void* d_ws, size_t ws_size,
                              hipStream_t stream) {
    const float* x      = (const float*)d_in[0];
    const float* net_w  = (const float*)d_in[1];
    const float* net_b  = (const float*)d_in[2];
    const float* lam_w  = (const float*)d_in[3];
    const float* lam_b  = (const float*)d_in[4];
    const float* mlp_w1 = (const float*)d_in[5];
    const float* bn_g   = (const float*)d_in[6];
    const float* bn_b   = (const float*)d_in[7];
    const float* bn_m   = (const float*)d_in[8];
    const float* bn_v   = (const float*)d_in[9];
    const float* mlp_w2 = (const float*)d_in[10];
    const float* me_w   = (const float*)d_in[11];
    float* out = (float*)d_out;

    char* ws = (char*)d_ws;
    unsigned short* xt  = (unsigned short*)(ws + OFF_XT);
    unsigned short* wpk = (unsigned short*)(ws + OFF_WPK);
    float* chansum = (float*)(ws + OFF_CS);
    float* xg2     = (float*)(ws + OFF_XG2);
    float* wgt     = (float*)(ws + OFF_WGT);
    float* gate    = (float*)(ws + OFF_GATE);
    unsigned short* cvt = (unsigned short*)(ws + OFF_CVT);

    const bool use_bf16 = (ws_size >= OFF_CVT + SZ_CVT);

    hipMemsetAsync(chansum, 0, SZ_CS, stream);
    kw_pack<<<2304, 256, 0, stream>>>(net_w, wpk);
    kinit<<<4096, 256, 0, stream>>>(net_b, out, chansum);
    k0_transpose<<<64 * 56 * 4, 256, 0, stream>>>(x, xt);
    if (use_bf16)
        conv_mfma<1><<<1664, 512, 0, stream>>>(xt, wpk, net_b, out, cvt, chansum);
    else
        conv_mfma<0><<<1664, 512, 0, stream>>>(xt, wpk, net_b, out, cvt, chansum);
    k234<<<8, 256, 0, stream>>>(chansum, lam_w, lam_b, mlp_w1, bn_g, bn_b, bn_m, bn_v,
                                mlp_w2, me_w, xg2, wgt, gate);
    if (use_bf16)
        k5_final<1><<<6272, 256, 0, stream>>>(out, cvt, wgt, xg2, gate);
    else
        k5_final<0><<<6272, 256, 0, stream>>>(out, cvt, wgt, xg2, gate);
}

// Round 18
// 405.941 us; speedup vs baseline: 1.0259x; 1.0259x over previous
//
#include <hip/hip_runtime.h>
#include <hip/hip_bf16.h>
#include <stdint.h>

#define AS1 __attribute__((address_space(1)))
#define AS3 __attribute__((address_space(3)))

typedef __attribute__((ext_vector_type(8))) short short8v;
typedef __attribute__((ext_vector_type(4))) unsigned short ushort4v;
typedef __attribute__((ext_vector_type(4))) float float4v;

#define NT 64
#define CCH 256
#define HH 56
#define WW 56
#define HWSZ 3136
#define HP 58
#define WP 58
#define TAILP 196608    // first tail pixel (tiles 1536..1567)

// workspace layout (bytes)
#define OFF_XT   0ull
#define SZ_XT    110231552ull          // 64*58*58*256*2  (bf16 NHWC padded)
#define OFF_WPK  (OFF_XT + SZ_XT)
#define SZ_WPK   1179648ull            // 9*256*256*2
#define OFF_CS   (OFF_WPK + SZ_WPK)
#define SZ_CS    65536ull              // 64*256 f32 channel sums
#define OFF_XG2  (OFF_CS + SZ_CS)
#define SZ_XG2   8192ull               // 8*256 f32
#define OFF_WGT  (OFF_XG2 + SZ_XG2)
#define SZ_WGT   24576ull              // 8*256*3 f32
#define OFF_GATE (OFF_WGT + SZ_WGT)
#define SZ_GATE  65536ull              // 64*256 f32
#define OFF_CVT  (OFF_GATE + SZ_GATE)
#define SZ_CVT   102760448ull          // 200704*256 bf16 conv output

__device__ __forceinline__ unsigned short f2bf(float f) {
    unsigned int u = __float_as_uint(f);
    unsigned int r = (u + 0x7fffu + ((u >> 16) & 1u)) >> 16;
    return (unsigned short)r;
}
__device__ __forceinline__ float bf2f(unsigned short u) {
    return __uint_as_float(((unsigned int)u) << 16);
}

__device__ __forceinline__ void gload16(const unsigned short* g, unsigned short* l) {
    __builtin_amdgcn_global_load_lds((const AS1 void*)g, (AS3 void*)l, 16, 0, 0);
}

// ---------------- K0: NCHW f32 -> NHWC-padded bf16 (with zero borders) ----
__global__ __launch_bounds__(256) void k0_transpose(const float* __restrict__ x,
                                                    unsigned short* __restrict__ xt) {
    int b = blockIdx.x;              // (nt, h, cb) : 64*56*4
    int cb = b & 3;
    int h  = (b >> 2) % 56;
    int nt = b / (4 * 56);
    int c0 = cb * 64;
    int tid = threadIdx.x;

    __shared__ float xs[64 * 57];    // padded stride 57 to dodge bank conflicts

    const float* src = x + ((size_t)nt * CCH + c0) * HWSZ + h * WW;
    for (int li = tid; li < 896; li += 256) {       // 64 rows * 14 float4
        int row = li / 14, f4 = li % 14;
        float4v v = *(const float4v*)(src + (size_t)row * HWSZ + f4 * 4);
        float* d = &xs[row * 57 + f4 * 4];
        d[0] = v.x; d[1] = v.y; d[2] = v.z; d[3] = v.w;
    }
    __syncthreads();

    unsigned short* dst = xt + (((size_t)nt * HP + (h + 1)) * WP) * CCH + c0;
    for (int job = tid; job < 464; job += 256) {    // 58 ww * 8 cgroups
        int ww = job >> 3, cg = job & 7;
        short8v v;
        if (ww == 0 || ww == 57) {
            v = (short8v){0,0,0,0,0,0,0,0};
        } else {
            #pragma unroll
            for (int jj = 0; jj < 8; ++jj)
                v[jj] = (short)f2bf(xs[(cg * 8 + jj) * 57 + (ww - 1)]);
        }
        *(short8v*)(dst + ww * CCH + cg * 8) = v;
    }
    if (h == 0) {   // zero rows hh=0 and hh=57
        unsigned short* d0  = xt + ((size_t)nt * HP + 0)  * WP * CCH + c0;
        unsigned short* d57 = xt + ((size_t)nt * HP + 57) * WP * CCH + c0;
        short8v z = (short8v){0,0,0,0,0,0,0,0};
        for (int job = tid; job < 464; job += 256) {
            int ww = job >> 3, cg = job & 7;
            *(short8v*)(d0  + ww * CCH + cg * 8) = z;
            *(short8v*)(d57 + ww * CCH + cg * 8) = z;
        }
    }
}

// ---------------- KW: pack conv weights -> [rs][k][c] bf16 ----------------
__global__ __launch_bounds__(256) void kw_pack(const float* __restrict__ nw,
                                               unsigned short* __restrict__ wpk) {
    int idx = blockIdx.x * 256 + threadIdx.x;       // 9*256*256 = 589824
    int rs = idx >> 16;
    int k  = (idx >> 8) & 255;
    int c  = idx & 255;
    wpk[idx] = f2bf(nw[(k * 256 + c) * 9 + rs]);
}

// ---------------- KI: init tail region of out (bias) + chansum bias terms -
// Tail pixels [196608, 200704): images 62 (hw>=2176, 960px) and 63 (all).
__global__ __launch_bounds__(256) void kinit(const float* __restrict__ net_b,
                                             float* __restrict__ out,
                                             float* __restrict__ chansum) {
    int idx = blockIdx.x * 256 + threadIdx.x;    // 1,048,576
    int m  = idx >> 12;          // 0..255
    int pp = idx & 4095;         // 0..4095
    int p  = TAILP + pp;
    int nt = p / HWSZ, hw = p - nt * HWSZ;
    out[((size_t)nt * CCH + m) * HWSZ + hw] = net_b[m];
    if (pp < 512) {              // 2 images x 256 channels
        int img = 62 + (pp >> 8);
        int mm  = pp & 255;
        float npix = (img == 62) ? 960.f : 3136.f;
        chansum[img * CCH + mm] = npix * net_b[mm];
    }
}

// ---------------- conv: implicit GEMM, 256x128x32 (R11 structure) ---------
// Blocks 0..1535: one full tile each (R11 inner loop, best measured).
// Blocks 1536..1599 (dispatched LAST): 2-way split-K halves (36 ktiles) of
// the 32 tail tiles -> round 4 shrinks from T to T/2 (makespan 4T -> 3.5T).
// Tail partials accumulate f32 atomicAdd into out (kinit pre-wrote bias);
// k5 reads tail pixels from out(f32), the rest from cvt(bf16).

#define STGALL(bi_, tA_, tB_) do { \
    gload16(wpk + (tA_) + aoffg0, &lds[(bi_) * 8192 + ldsa0]); \
    gload16(wpk + (tA_) + aoffg1, &lds[(bi_) * 8192 + ldsa1]); \
    gload16(xt  + (tB_) + boffg,  &lds[24576 + (bi_) * 4096 + ldsb]); \
} while (0)

#define LDAF(mi) (*(const short8v*)&lds[abase + (wm * 64 + (mi) * 16 + r16) * 32 + pA * 8])
#define LDBF(j)  (*(const short8v*)&lds[bbase + (wp * 64 + (j) * 16 + r16) * 32 + pA * 8])

#define KTA(kt) ((((kt) >> 3) << 16) + (((kt) & 7) * 32))
#define KTB(kt) (((((kt) >> 3) / 3) * WP + (((kt) >> 3) - (((kt) >> 3) / 3) * 3)) * 256 + (((kt) & 7) * 32))

#define BARSYNC do { \
    __builtin_amdgcn_s_barrier(); \
    __builtin_amdgcn_sched_barrier(0); \
} while (0)

#define KTILE_BODY \
    short8v afrag[4], bfrag[4]; \
    _Pragma("unroll") \
    for (int mi = 0; mi < 4; ++mi) afrag[mi] = LDAF(mi); \
    _Pragma("unroll") \
    for (int j = 0; j < 4; ++j) bfrag[j] = LDBF(j); \
    asm volatile("s_waitcnt lgkmcnt(0)" ::: "memory"); \
    __builtin_amdgcn_sched_barrier(0); \
    __builtin_amdgcn_s_setprio(1); \
    _Pragma("unroll") \
    for (int j = 0; j < 4; ++j) \
        _Pragma("unroll") \
        for (int mi = 0; mi < 4; ++mi) \
            acc[mi][j] = __builtin_amdgcn_mfma_f32_16x16x32_bf16(afrag[mi], bfrag[j], acc[mi][j], 0, 0, 0); \
    __builtin_amdgcn_s_setprio(0); \
    BARSYNC;

template <int OB>
__global__ __launch_bounds__(512, 4) void conv_mfma(const unsigned short* __restrict__ xt,
                                                    const unsigned short* __restrict__ wpk,
                                                    const float* __restrict__ net_b,
                                                    float* __restrict__ out,
                                                    unsigned short* __restrict__ cvt,
                                                    float* __restrict__ chansum) {
    __shared__ unsigned short lds[36864];  // 72 KB: A ring 3x8192, B ring 3x4096

    const int tid  = threadIdx.x;
    const int lane = tid & 63;
    const int wid  = tid >> 6;         // 0..7
    const int wm   = wid >> 1;         // 0..3  (m quarter, 64 rows)
    const int wp   = wid & 1;          // 0..1  (pixel half, 64 px)
    const int r16  = lane & 15;
    const int hi   = lane >> 4;        // 0..3  (k-chunk)
    const int pA   = (hi + (r16 >> 1)) & 3;   // rotation-swizzle read position

    const int bid = blockIdx.x;

    // A staging precompute: slot s -> row r = s>>2, pos p = s&3 holds global
    // chunk cg = (p - (r>>1)) & 3; 4 lanes/row cover 64 B contiguous.
    const int cgs = ((tid & 3) - (tid >> 3)) & 3;
    const int aoffg0 = (tid >> 2) * 256 + cgs * 8;   // A rows 0..127
    const int aoffg1 = aoffg0 + 32768;               // A rows 128..255
    const int ldsa0  = tid * 8;
    const int ldsa1  = ldsa0 + 4096;
    const int ldsb   = tid * 8;

    float4v acc[4][4];
    #pragma unroll
    for (int i = 0; i < 4; ++i)
        #pragma unroll
        for (int j = 0; j < 4; ++j) acc[i][j] = (float4v){0.f, 0.f, 0.f, 0.f};

    if (bid < 1536) {
        // ---------- regular: one full tile ----------
        // XCD-aware bijective swizzle: 1536 = 8 * 192
        const int pb0 = (bid & 7) * 192 + (bid >> 3);
        const int p0 = pb0 * 128;

        long boffg;
        {
            int r = tid >> 2;              // pixel row 0..127
            int p = p0 + r;
            int nt = p / HWSZ, hw = p - nt * HWSZ;
            int hh = hw / WW,  w  = hw - hh * WW;
            boffg = ((long)(nt * HP + hh) * WP + w) * 256 + cgs * 8;
        }

        STGALL(0, 0, 0);
        STGALL(1, 32, 32);

        int cur = 0;
        for (int kt = 0; kt < 72; ++kt) {
            const int abase = cur * 8192;
            const int bbase = 24576 + cur * 4096;

            if (kt < 70) {
                const int ktn = kt + 2;
                int nb2 = cur + 2; if (nb2 >= 3) nb2 -= 3;
                STGALL(nb2, KTA(ktn), KTB(ktn));
                asm volatile("s_waitcnt vmcnt(6)" ::: "memory");
            } else if (kt == 70) {
                asm volatile("s_waitcnt vmcnt(3)" ::: "memory");
            } else {
                asm volatile("s_waitcnt vmcnt(0)" ::: "memory");
            }
            BARSYNC;

            KTILE_BODY
            ++cur; if (cur >= 3) cur = 0;
        }

        // epilogue: bias + store + fused channel-sum
        const int pw = p0 + wp * 64;
        const int ntw = pw / HWSZ;
        const int hwb = pw - ntw * HWSZ;
        #pragma unroll
        for (int mi = 0; mi < 4; ++mi) {
            #pragma unroll
            for (int r = 0; r < 4; ++r) {
                const int m = wm * 64 + mi * 16 + hi * 4 + r;
                const float bias = net_b[m];
                float csum = 0.f;
                const size_t obase = ((size_t)ntw * CCH + m) * HWSZ + hwb;
                #pragma unroll
                for (int j = 0; j < 4; ++j) {
                    float v = acc[mi][j][r] + bias;
                    if (OB) cvt[obase + j * 16 + r16] = f2bf(v);
                    else    out[obase + j * 16 + r16] = v;
                    csum += v;
                }
                csum += __shfl_xor(csum, 1);
                csum += __shfl_xor(csum, 2);
                csum += __shfl_xor(csum, 4);
                csum += __shfl_xor(csum, 8);
                if (r16 == 0) atomicAdd(&chansum[ntw * CCH + m], csum);
            }
        }
    } else {
        // ---------- tail: half-K of one of the 32 tail tiles ----------
        const int tb = bid - 1536;           // 0..63
        const int p0 = (1536 + (tb >> 1)) * 128;
        const int k0 = (tb & 1) * 36;

        long boffg;
        {
            int r = tid >> 2;
            int p = p0 + r;
            int nt = p / HWSZ, hw = p - nt * HWSZ;
            int hh = hw / WW,  w  = hw - hh * WW;
            boffg = ((long)(nt * HP + hh) * WP + w) * 256 + cgs * 8;
        }

        STGALL(0, KTA(k0), KTB(k0));
        STGALL(1, KTA(k0 + 1), KTB(k0 + 1));

        int cur = 0;
        for (int i = 0; i < 36; ++i) {
            const int abase = cur * 8192;
            const int bbase = 24576 + cur * 4096;

            if (i < 34) {
                int nb2 = cur + 2; if (nb2 >= 3) nb2 -= 3;
                const int ktn = k0 + i + 2;
                STGALL(nb2, KTA(ktn), KTB(ktn));
                asm volatile("s_waitcnt vmcnt(6)" ::: "memory");
            } else if (i == 34) {
                asm volatile("s_waitcnt vmcnt(3)" ::: "memory");
            } else {
                asm volatile("s_waitcnt vmcnt(0)" ::: "memory");
            }
            BARSYNC;

            KTILE_BODY
            ++cur; if (cur >= 3) cur = 0;
        }

        // tail epilogue: atomic accumulate into f32 out (no bias), csum
        const int pw = p0 + wp * 64;
        const int ntw = pw / HWSZ;
        const int hwb = pw - ntw * HWSZ;
        #pragma unroll
        for (int mi = 0; mi < 4; ++mi) {
            #pragma unroll
            for (int r = 0; r < 4; ++r) {
                const int m = wm * 64 + mi * 16 + hi * 4 + r;
                float csum = 0.f;
                float* orow = out + ((size_t)ntw * CCH + m) * HWSZ + hwb;
                #pragma unroll
                for (int j = 0; j < 4; ++j) {
                    float v = acc[mi][j][r];
                    atomicAdd(&orow[j * 16 + r16], v);
                    csum += v;
                }
                csum += __shfl_xor(csum, 1);
                csum += __shfl_xor(csum, 2);
                csum += __shfl_xor(csum, 4);
                csum += __shfl_xor(csum, 8);
                if (r16 == 0) atomicAdd(&chansum[ntw * CCH + m], csum);
            }
        }
    }
}

// ---------------- K234: fused x_g -> MLP/BN/softmax -> ME gate ------------
__global__ __launch_bounds__(256) void k234(const float* __restrict__ chansum,
                                            const float* __restrict__ lam_w,
                                            const float* __restrict__ lam_b,
                                            const float* __restrict__ mw1,
                                            const float* __restrict__ bg,
                                            const float* __restrict__ bb,
                                            const float* __restrict__ bm,
                                            const float* __restrict__ bv,
                                            const float* __restrict__ mw2,
                                            const float* __restrict__ me_w,
                                            float* __restrict__ xg2,
                                            float* __restrict__ wgt,
                                            float* __restrict__ gate) {
    int n = blockIdx.x, c = threadIdx.x;
    __shared__ float xs[256];
    __shared__ float yd[8][256];

    float s = 0.f;
    #pragma unroll
    for (int t = 0; t < 8; ++t) s += chansum[(n * 8 + t) * CCH + c];
    xs[c] = s * (1.0f / (3136.f * 8.f));
    __syncthreads();

    float xg = lam_b[c];
    const float* row = lam_w + c * 256;
    for (int cc = 0; cc < 256; ++cc) xg += row[cc] * xs[cc];
    xg2[n * 256 + c] = xg;

    float p[8];
    #pragma unroll
    for (int t = 0; t < 8; ++t)
        p[t] = chansum[(n * 8 + t) * CCH + c] * (1.0f / 3136.f) + xg;

    float hd[16];
    #pragma unroll
    for (int j = 0; j < 16; ++j) {
        float v = 0.f;
        #pragma unroll
        for (int t = 0; t < 8; ++t) v += p[t] * mw1[j * 8 + t];
        v = (v - bm[j]) * (bg[j] * rsqrtf(bv[j] + 1e-5f)) + bb[j];
        hd[j] = fmaxf(v, 0.f);
    }
    float lg[3];
    #pragma unroll
    for (int k = 0; k < 3; ++k) {
        float v = 0.f;
        #pragma unroll
        for (int j = 0; j < 16; ++j) v += hd[j] * mw2[k * 16 + j];
        lg[k] = v;
    }
    float mx = fmaxf(fmaxf(lg[0], lg[1]), lg[2]);
    float e0 = expf(lg[0] - mx), e1 = expf(lg[1] - mx), e2 = expf(lg[2] - mx);
    float inv = 1.f / (e0 + e1 + e2);
    float wk[3] = {e0 * inv, e1 * inv, e2 * inv};
    int idx = n * 256 + c;
    #pragma unroll
    for (int k = 0; k < 3; ++k) wgt[idx * 3 + k] = wk[k];

    float mb[8];
    #pragma unroll
    for (int t = 0; t < 8; ++t) {
        float v = 0.f;
        #pragma unroll
        for (int k = 0; k < 3; ++k) {
            int tt = t + k - 1;
            if (tt >= 0 && tt < 8) v += wk[k] * p[tt];
        }
        mb[t] = v;
    }
    #pragma unroll
    for (int t = 0; t < 7; ++t) yd[t][c] = mb[t + 1] - mb[t];
    yd[7][c] = 0.f;
    __syncthreads();

    float w0 = me_w[0], w1v = me_w[1], w2v = me_w[2];
    #pragma unroll
    for (int t = 0; t < 8; ++t) {
        float yc = w1v * yd[t][c];
        if (c > 0)   yc += w0 * yd[t][c - 1];
        if (c < 255) yc += w2v * yd[t][c + 1];
        gate[(n * 8 + t) * CCH + c] = 1.f / (1.f + expf(-yc));
    }
}

// ---------------- K5: temporal mix + gate -> d_out ------------------------
template <int OB>
__global__ __launch_bounds__(256) void k5_final(float* __restrict__ out,
                                                const unsigned short* __restrict__ cvt,
                                                const float* __restrict__ wgt,
                                                const float* __restrict__ xg2,
                                                const float* __restrict__ gate) {
    int tid = blockIdx.x * 256 + threadIdx.x;   // 2048 * 784
    int hw4 = tid % 784;
    int nc = tid / 784;
    int n = nc >> 8, c = nc & 255;
    float w0 = wgt[nc * 3 + 0], w1 = wgt[nc * 3 + 1], w2 = wgt[nc * 3 + 2];
    float xg = xg2[nc];
    const size_t tstride = (size_t)CCH * HWSZ;
    size_t base = ((size_t)(n * 8) * CCH + c) * HWSZ + hw4 * 4;

    float4v o[8];
    #pragma unroll
    for (int t = 0; t < 8; ++t) {
        size_t addr = base + t * tstride;
        if (OB) {
            int p = (n * 8 + t) * HWSZ + hw4 * 4;   // global pixel index
            if (p >= TAILP) {                        // tail: f32 in out
                o[t] = *(const float4v*)(out + addr);
            } else {
                ushort4v v = *(const ushort4v*)(cvt + addr);
                #pragma unroll
                for (int q = 0; q < 4; ++q) o[t][q] = bf2f(v[q]);
            }
        } else {
            o[t] = *(const float4v*)(out + addr);
        }
    }

    #pragma unroll
    for (int t = 0; t < 8; ++t) {
        float g = gate[(n * 8 + t) * CCH + c];
        float4v lam;
        #pragma unroll
        for (int q = 0; q < 4; ++q) {
            float v = w1 * (o[t][q] + xg);
            if (t > 0) v += w0 * (o[t - 1][q] + xg);
            if (t < 7) v += w2 * (o[t + 1][q] + xg);
            lam[q] = g * v;
        }
        *(float4v*)(out + base + t * tstride) = lam;
    }
}

extern "C" void kernel_launch(void* const* d_in, const int* in_sizes, int n_in,
                              void* d_out, int out_size, void* d_ws, size_t ws_size,
                              hipStream_t stream) {
    const float* x      = (const float*)d_in[0];
    const float* net_w  = (const float*)d_in[1];
    const float* net_b  = (const float*)d_in[2];
    const float* lam_w  = (const float*)d_in[3];
    const float* lam_b  = (const float*)d_in[4];
    const float* mlp_w1 = (const float*)d_in[5];
    const float* bn_g   = (const float*)d_in[6];
    const float* bn_b   = (const float*)d_in[7];
    const float* bn_m   = (const float*)d_in[8];
    const float* bn_v   = (const float*)d_in[9];
    const float* mlp_w2 = (const float*)d_in[10];
    const float* me_w   = (const float*)d_in[11];
    float* out = (float*)d_out;

    char* ws = (char*)d_ws;
    unsigned short* xt  = (unsigned short*)(ws + OFF_XT);
    unsigned short* wpk = (unsigned short*)(ws + OFF_WPK);
    float* chansum = (float*)(ws + OFF_CS);
    float* xg2     = (float*)(ws + OFF_XG2);
    float* wgt     = (float*)(ws + OFF_WGT);
    float* gate    = (float*)(ws + OFF_GATE);
    unsigned short* cvt = (unsigned short*)(ws + OFF_CVT);

    const bool use_bf16 = (ws_size >= OFF_CVT + SZ_CVT);

    hipMemsetAsync(chansum, 0, SZ_CS, stream);
    kw_pack<<<2304, 256, 0, stream>>>(net_w, wpk);
    kinit<<<4096, 256, 0, stream>>>(net_b, out, chansum);
    k0_transpose<<<64 * 56 * 4, 256, 0, stream>>>(x, xt);
    if (use_bf16)
        conv_mfma<1><<<1600, 512, 0, stream>>>(xt, wpk, net_b, out, cvt, chansum);
    else
        conv_mfma<0><<<1600, 512, 0, stream>>>(xt, wpk, net_b, out, cvt, chansum);
    k234<<<8, 256, 0, stream>>>(chansum, lam_w, lam_b, mlp_w1, bn_g, bn_b, bn_m, bn_v,
                                mlp_w2, me_w, xg2, wgt, gate);
    if (use_bf16)
        k5_final<1><<<6272, 256, 0, stream>>>(out, cvt, wgt, xg2, gate);
    else
        k5_final<0><<<6272, 256, 0, stream>>>(out, cvt, wgt, xg2, gate);
}